// Round 2
// baseline (14054.236 us; speedup 1.0000x reference)
//
#include <hip/hip_runtime.h>
#include <math.h>

#define EPSF     0.1f
#define BB       8
#define NN       2048
#define DIM      32
#define MAX_ITER 100
#define THRESHF  0.1f
#define NSLOT    16
#define NGRP     16
#define GRPSZ    32
// base-2 domain constants: exp(x) = exp2(x*log2e)
#define C20L2E 28.853900817779268f   // (2/EPS)*log2e
#define C10L2E 14.426950408889634f   // (1/EPS)*log2e
#define LN2F   0.6931471805599453f

typedef __attribute__((ext_vector_type(8))) short  sh8;    // 8 x bf16 (4 VGPRs)
typedef __attribute__((ext_vector_type(4))) float  f32x4;  // MFMA C/D

__device__ __forceinline__ float ex2(float x) { return __builtin_amdgcn_exp2f(x); }
__device__ __forceinline__ float lg2(float x) { return __builtin_amdgcn_logf(x); }

__device__ __forceinline__ unsigned short bf16_rne(float v) {
  unsigned u = __float_as_uint(v);
  unsigned r = (u + 0x7FFFu + ((u >> 16) & 1u)) >> 16;
  return (unsigned short)r;
}

// Split fp32 -> bf16 hi/lo, compute row |.|^2 and initial w2 = 10*log2e*(0 - |.|^2).
__global__ __launch_bounds__(256) void prep_kernel(const float* __restrict__ in,
                                                   unsigned short* __restrict__ hi,
                                                   unsigned short* __restrict__ lo,
                                                   float* __restrict__ snorm,
                                                   float* __restrict__ w2init) {
  const int tid = blockIdx.x * 256 + threadIdx.x;
  const int row = tid >> 5, k = tid & 31;
  float val = in[tid];
  unsigned short h = bf16_rne(val);
  float hf = __uint_as_float(((unsigned)h) << 16);
  unsigned short l = bf16_rne(val - hf);
  hi[tid] = h;
  lo[tid] = l;
  float sq = val * val;
#pragma unroll
  for (int off = 1; off < 32; off <<= 1) sq += __shfl_xor(sq, off, 64);
  if (k == 0) {
    snorm[row] = sq;
    w2init[row] = -sq * C10L2E;
  }
  (void)k;
}

// Hierarchical monotonic grid barrier: 16 groups x 32 blocks, device-scope atomics.
// Counters are never reset (targets scale with barno) -> no reset races.
__device__ __forceinline__ void grid_barrier(int* __restrict__ gcnt,
                                             int* __restrict__ root,
                                             int barno, int g) {
  __syncthreads();
  if (threadIdx.x == 0) {
    __threadfence();   // release all prior global writes (agent scope)
    int t = __hip_atomic_fetch_add(&gcnt[g * 32], 1, __ATOMIC_ACQ_REL,
                                   __HIP_MEMORY_SCOPE_AGENT);
    if (t == barno * GRPSZ + (GRPSZ - 1)) {
      __hip_atomic_fetch_add(root, 1, __ATOMIC_ACQ_REL, __HIP_MEMORY_SCOPE_AGENT);
    }
    const int target = barno * NGRP + NGRP;
    while (__hip_atomic_load(root, __ATOMIC_ACQUIRE, __HIP_MEMORY_SCOPE_AGENT) < target) {
      __builtin_amdgcn_s_sleep(1);
    }
    __threadfence();   // acquire: invalidate stale cached lines
  }
  __syncthreads();
}

// One half-sweep for this block's 32 rows. S = A.B^T recomputed via split-bf16 MFMA.
// WG=256 (4 waves), each wave covers a 512-col j-quarter; 4-way LSE merge in LDS.
// Online LSE uses ONE exp2 per element: e = exp2(-|t-m|), select update.
__device__ __forceinline__ void sweep_phase(
    const unsigned short* __restrict__ Ah, const unsigned short* __restrict__ Al,
    const unsigned short* __restrict__ Bh, const unsigned short* __restrict__ Bl,
    const float* __restrict__ sa, float* __restrict__ selfD,
    float* __restrict__ wself2, const float* __restrict__ woth2,
    float* __restrict__ slots, const bool isRow,
    const int b, const int i0, const int g, const float cst,
    float lm[32][4], float ls[32][4]) {
  const int wq   = threadIdx.x >> 6;
  const int lane = threadIdx.x & 63;
  const int l15  = lane & 15, q = lane >> 4;

  // fixed A fragments: rows i0+l15 (acc0) and i0+16+l15 (acc1), k-chunk q*8
  const size_t arow0 = ((size_t)(b * NN + i0 + l15)) * DIM + q * 8;
  const sh8 a0h = *(const sh8*)(Ah + arow0);
  const sh8 a0l = *(const sh8*)(Al + arow0);
  const sh8 a1h = *(const sh8*)(Ah + arow0 + 16 * DIM);
  const sh8 a1l = *(const sh8*)(Al + arow0 + 16 * DIM);

  float m2[8], ss[8];
#pragma unroll
  for (int r = 0; r < 8; r++) { m2[r] = -1e30f; ss[r] = 0.f; }

  const int jbase = wq * 512;
#pragma unroll 4
  for (int tj = 0; tj < 32; tj++) {
    const int j = jbase + tj * 16;
    const size_t brow = ((size_t)(b * NN + j + l15)) * DIM + q * 8;
    const sh8 bh = *(const sh8*)(Bh + brow);
    const sh8 bl = *(const sh8*)(Bl + brow);
    f32x4 acc0 = {0.f, 0.f, 0.f, 0.f};
    f32x4 acc1 = {0.f, 0.f, 0.f, 0.f};
    acc0 = __builtin_amdgcn_mfma_f32_16x16x32_bf16(a0h, bh, acc0, 0, 0, 0);
    acc1 = __builtin_amdgcn_mfma_f32_16x16x32_bf16(a1h, bh, acc1, 0, 0, 0);
    acc0 = __builtin_amdgcn_mfma_f32_16x16x32_bf16(a0h, bl, acc0, 0, 0, 0);
    acc1 = __builtin_amdgcn_mfma_f32_16x16x32_bf16(a1h, bl, acc1, 0, 0, 0);
    acc0 = __builtin_amdgcn_mfma_f32_16x16x32_bf16(a0l, bh, acc0, 0, 0, 0);
    acc1 = __builtin_amdgcn_mfma_f32_16x16x32_bf16(a1l, bh, acc1, 0, 0, 0);
    const float wj = woth2[b * NN + j + l15];
#pragma unroll
    for (int r = 0; r < 8; r++) {
      const float S = (r < 4) ? acc0[r & 3] : acc1[r & 3];
      const float t = fmaf(S, C20L2E, wj);
      const float d = t - m2[r];
      const float e = ex2(-fabsf(d));           // single transcendental
      const bool up = d > 0.f;
      ss[r] = up ? fmaf(ss[r], e, 1.f) : (ss[r] + e);
      m2[r] = up ? t : m2[r];
    }
  }

  // reduce (m,s) across the 16 lanes that share a row
#pragma unroll
  for (int off = 1; off < 16; off <<= 1) {
#pragma unroll
    for (int r = 0; r < 8; r++) {
      const float mo = __shfl_xor(m2[r], off, 64);
      const float so = __shfl_xor(ss[r], off, 64);
      const float mn = fmaxf(m2[r], mo);
      ss[r] = ss[r] * ex2(m2[r] - mn) + so * ex2(mo - mn);
      m2[r] = mn;
    }
  }

  if (l15 == 0) {
#pragma unroll
    for (int r = 0; r < 4; r++) {
      lm[q * 4 + r][wq] = m2[r];          ls[q * 4 + r][wq] = ss[r];
      lm[16 + q * 4 + r][wq] = m2[4 + r]; ls[16 + q * 4 + r][wq] = ss[4 + r];
    }
  }
  __syncthreads();
  if (threadIdx.x < 32) {
    const int row = threadIdx.x;
    float m = lm[row][0], s = ls[row][0];
#pragma unroll
    for (int p = 1; p < 4; p++) {
      const float mo = lm[row][p], so = ls[row][p];
      const float mn = fmaxf(m, mo);
      s = s * ex2(m - mn) + so * ex2(mo - mn);
      m = mn;
    }
    const float lse = (m + lg2(s)) * LN2F;   // natural-log LSE
    const int gi = b * NN + i0 + row;
    const float sav = sa[gi];
    const float nu = cst + sav - EPSF * lse;
    const float old = selfD[gi];
    selfD[gi] = nu;
    wself2[gi] = (nu - sav) * C10L2E;
    if (isRow) {
      float du = fabsf(nu - old);
#pragma unroll
      for (int off = 1; off < 32; off <<= 1) du += __shfl_xor(du, off, 64);
      if (threadIdx.x == 0) atomicAdd(&slots[g * 32], du);  // device-scope by default
    }
  }
  __syncthreads();
}

// Persistent (plain-launch) kernel: whole Sinkhorn loop, one dispatch.
// 512 WGs x 256 thr; launch_bounds(256,4) -> VGPR<=128 -> capacity 4 WG/CU = 1024
// >= 512: all blocks resident with 2x slack -> software grid barrier is safe.
__global__ __launch_bounds__(256, 4) void solve_kernel(
    const unsigned short* __restrict__ xh, const unsigned short* __restrict__ xl,
    const unsigned short* __restrict__ yh, const unsigned short* __restrict__ yl,
    const float* __restrict__ sx, const float* __restrict__ sy,
    float* __restrict__ u, float* __restrict__ v,
    float* __restrict__ wu2, float* __restrict__ wv2,
    float* __restrict__ slots, int* __restrict__ gcnt,
    int* __restrict__ root, int* __restrict__ done,
    float emu, float enu) {
  __shared__ float lm[32][4];
  __shared__ float ls[32][4];
  const int b  = blockIdx.x >> 6;
  const int i0 = (blockIdx.x & 63) * 32;
  const int g  = blockIdx.x & (NGRP - 1);
  int barno = 0;

  for (int it = 0; it < MAX_ITER; ++it) {
    // u-phase: rows of x vs all y, weights wv2 -> updates u, wu2, err slots
    sweep_phase(xh, xl, yh, yl, sx, u, wu2, wv2, slots, true, b, i0, g, emu, lm, ls);
    grid_barrier(gcnt, root, barno++, g);
    if (blockIdx.x == 0 && threadIdx.x == 0) {
      float e = 0.f;
      for (int s = 0; s < NSLOT; ++s) {
        e += __hip_atomic_load(&slots[s * 32], __ATOMIC_RELAXED, __HIP_MEMORY_SCOPE_AGENT);
        __hip_atomic_store(&slots[s * 32], 0.f, __ATOMIC_RELAXED, __HIP_MEMORY_SCOPE_AGENT);
      }
      if (e * 0.125f < THRESHF)
        __hip_atomic_store(done, 1, __ATOMIC_RELEASE, __HIP_MEMORY_SCOPE_AGENT);
    }
    // v-phase: rows of y vs all x, weights (updated) wu2 -> updates v, wv2
    sweep_phase(yh, yl, xh, xl, sy, v, wv2, wu2, slots, false, b, i0, g, enu, lm, ls);
    grid_barrier(gcnt, root, barno++, g);
    if (__hip_atomic_load(done, __ATOMIC_ACQUIRE, __HIP_MEMORY_SCOPE_AGENT))
      break;   // converging iteration applied; remaining iterations frozen
  }
}

// C = sx_i + sy_j - 2S ; pi = exp2(wu2_i + wv2_j + 20log2e*S) ; cost[b] += pi*C
__global__ __launch_bounds__(256) void finalize_kernel(const unsigned short* __restrict__ xh,
                                                       const unsigned short* __restrict__ xl,
                                                       const unsigned short* __restrict__ yh,
                                                       const unsigned short* __restrict__ yl,
                                                       const float* __restrict__ sx,
                                                       const float* __restrict__ sy,
                                                       const float* __restrict__ wu2,
                                                       const float* __restrict__ wv2,
                                                       float* __restrict__ C,
                                                       float* __restrict__ pi,
                                                       float* __restrict__ cost) {
  const int b  = blockIdx.z;
  const int wv = threadIdx.x >> 6;
  const int lane = threadIdx.x & 63;
  const int l15 = lane & 15, q = lane >> 4;
  const int i0 = blockIdx.y * 128 + wv * 32;
  const int j0 = blockIdx.x * 256;

  const size_t arow0 = ((size_t)(b * NN + i0 + l15)) * DIM + q * 8;
  const sh8 a0h = *(const sh8*)(xh + arow0);
  const sh8 a0l = *(const sh8*)(xl + arow0);
  const sh8 a1h = *(const sh8*)(xh + arow0 + 16 * DIM);
  const sh8 a1l = *(const sh8*)(xl + arow0 + 16 * DIM);

  float sx0[8], wu0[8];
#pragma unroll
  for (int r = 0; r < 8; r++) {
    const int gi = b * NN + i0 + ((r < 4) ? (q * 4 + (r & 3)) : (16 + q * 4 + (r & 3)));
    sx0[r] = sx[gi];
    wu0[r] = wu2[gi];
  }

  float acc = 0.f;
#pragma unroll 2
  for (int tj = 0; tj < 16; tj++) {
    const int j = j0 + tj * 16;
    const size_t brow = ((size_t)(b * NN + j + l15)) * DIM + q * 8;
    const sh8 bh = *(const sh8*)(yh + brow);
    const sh8 bl = *(const sh8*)(yl + brow);
    f32x4 acc0 = {0.f, 0.f, 0.f, 0.f};
    f32x4 acc1 = {0.f, 0.f, 0.f, 0.f};
    acc0 = __builtin_amdgcn_mfma_f32_16x16x32_bf16(a0h, bh, acc0, 0, 0, 0);
    acc1 = __builtin_amdgcn_mfma_f32_16x16x32_bf16(a1h, bh, acc1, 0, 0, 0);
    acc0 = __builtin_amdgcn_mfma_f32_16x16x32_bf16(a0h, bl, acc0, 0, 0, 0);
    acc1 = __builtin_amdgcn_mfma_f32_16x16x32_bf16(a1h, bl, acc1, 0, 0, 0);
    acc0 = __builtin_amdgcn_mfma_f32_16x16x32_bf16(a0l, bh, acc0, 0, 0, 0);
    acc1 = __builtin_amdgcn_mfma_f32_16x16x32_bf16(a1l, bh, acc1, 0, 0, 0);
    const int gj = b * NN + j + l15;
    const float syj = sy[gj];
    const float wvj = wv2[gj];
#pragma unroll
    for (int r = 0; r < 8; r++) {
      const float S = (r < 4) ? acc0[r & 3] : acc1[r & 3];
      const int irow = i0 + ((r < 4) ? (q * 4 + (r & 3)) : (16 + q * 4 + (r & 3)));
      const float Cv = fmaf(-2.f, S, sx0[r] + syj);
      const float p  = ex2(fmaf(S, C20L2E, wu0[r] + wvj));
      const size_t addr = ((size_t)(b * NN + irow)) * NN + j + l15;
      C[addr]  = Cv;
      pi[addr] = p;
      acc = fmaf(p, Cv, acc);
    }
  }
#pragma unroll
  for (int off = 1; off < 64; off <<= 1) acc += __shfl_xor(acc, off, 64);
  __shared__ float red[4];
  if (lane == 0) red[wv] = acc;
  __syncthreads();
  if (threadIdx.x == 0) atomicAdd(&cost[b], red[0] + red[1] + red[2] + red[3]);
}

extern "C" void kernel_launch(void* const* d_in, const int* in_sizes, int n_in,
                              void* d_out, int out_size, void* d_ws, size_t ws_size,
                              hipStream_t stream) {
  const float* x = (const float*)d_in[0];
  const float* y = (const float*)d_in[1];
  float* out  = (float*)d_out;
  float* cost = out;                              // [8]
  float* pi   = out + 8;                          // [8,2048,2048]
  float* C    = out + 8 + (size_t)BB * NN * NN;   // [8,2048,2048]

  float* ws = (float*)d_ws;
  const int BN = BB * NN;                         // 16384
  float* u   = ws;               // [16384]
  float* v   = ws + BN;
  float* wu2 = ws + 2 * BN;
  float* wv2 = ws + 3 * BN;
  float* sx  = ws + 4 * BN;
  float* sy  = ws + 5 * BN;
  float* slots = ws + 6 * BN;                     // 16 slots, stride 32 floats
  int*   gcnt  = (int*)(ws + 6 * BN + 512);       // 16 counters, stride 32 ints
  int*   root  = gcnt + 512;
  int*   done  = gcnt + 513;
  unsigned short* xh = (unsigned short*)(ws + 6 * BN + 512 + 576);
  const size_t NE = (size_t)BB * NN * DIM;        // 524288
  unsigned short* xl = xh + NE;
  unsigned short* yh = xh + 2 * NE;
  unsigned short* yl = xh + 3 * NE;

  // zero u,v,slots,barrier counters,done (prep rewrites wu2/wv2/sx/sy)
  hipMemsetAsync(d_ws, 0, (size_t)(6 * BN + 512 + 576) * sizeof(float), stream);
  hipMemsetAsync(d_out, 0, 8 * sizeof(float), stream);

  prep_kernel<<<2048, 256, 0, stream>>>(x, xh, xl, sx, wu2);
  prep_kernel<<<2048, 256, 0, stream>>>(y, yh, yl, sy, wv2);

  const float emu = (float)(0.1 * log(1.0 / 2048.0 + 1e-8));
  const float enu = emu;

  solve_kernel<<<512, 256, 0, stream>>>(xh, xl, yh, yl, sx, sy, u, v, wu2, wv2,
                                        slots, gcnt, root, done, emu, enu);

  finalize_kernel<<<dim3(8, 16, BB), 256, 0, stream>>>(xh, xl, yh, yl, sx, sy,
                                                       wu2, wv2, C, pi, cost);
}

// Round 3
// 4313.291 us; speedup vs baseline: 3.2584x; 3.2584x over previous
//
#include <hip/hip_runtime.h>
#include <math.h>

#define EPSF     0.1f
#define BB       8
#define NN       2048
#define DIM      32
#define MAX_ITER 100
#define THRESHF  0.1f
#define NSLOT    16
#define NGRP     16
#define GRPSZ    32
// base-2 domain constants: exp(x) = exp2(x*log2e)
#define C20L2E 28.853900817779268f   // (2/EPS)*log2e
#define C10L2E 14.426950408889634f   // (1/EPS)*log2e
#define LN2F   0.6931471805599453f

typedef __attribute__((ext_vector_type(8))) short  sh8;    // 8 x bf16 (4 VGPRs)
typedef __attribute__((ext_vector_type(4))) float  f32x4;  // MFMA C/D

__device__ __forceinline__ float ex2(float x) { return __builtin_amdgcn_exp2f(x); }
__device__ __forceinline__ float lg2(float x) { return __builtin_amdgcn_logf(x); }

// coherent (agent-scope, cache-bypassing) scalar access to cross-block data
__device__ __forceinline__ float coh_load(const float* p) {
  return __uint_as_float(__hip_atomic_load((const unsigned*)p, __ATOMIC_RELAXED,
                                           __HIP_MEMORY_SCOPE_AGENT));
}
__device__ __forceinline__ void coh_store(float* p, float v) {
  __hip_atomic_store((unsigned*)p, __float_as_uint(v), __ATOMIC_RELAXED,
                     __HIP_MEMORY_SCOPE_AGENT);
}

__device__ __forceinline__ unsigned short bf16_rne(float v) {
  unsigned u = __float_as_uint(v);
  unsigned r = (u + 0x7FFFu + ((u >> 16) & 1u)) >> 16;
  return (unsigned short)r;
}

// Split fp32 -> bf16 hi/lo, compute row |.|^2 and initial w2 = 10*log2e*(0 - |.|^2).
__global__ __launch_bounds__(256) void prep_kernel(const float* __restrict__ in,
                                                   unsigned short* __restrict__ hi,
                                                   unsigned short* __restrict__ lo,
                                                   float* __restrict__ snorm,
                                                   float* __restrict__ w2init) {
  const int tid = blockIdx.x * 256 + threadIdx.x;
  const int row = tid >> 5, k = tid & 31;
  float val = in[tid];
  unsigned short h = bf16_rne(val);
  float hf = __uint_as_float(((unsigned)h) << 16);
  unsigned short l = bf16_rne(val - hf);
  hi[tid] = h;
  lo[tid] = l;
  float sq = val * val;
#pragma unroll
  for (int off = 1; off < 32; off <<= 1) sq += __shfl_xor(sq, off, 64);
  if (k == 0) {
    snorm[row] = sq;
    w2init[row] = -sq * C10L2E;
  }
  (void)k;
}

// Invalidate-free grid barrier: 16 groups x 32 blocks, monotonic counters.
// All cross-block data goes through coherent (cache-bypassing) atomics, so no
// buffer_inv / buffer_wbl2 is ever needed: arrival only needs vmcnt(0) (acks of
// this wave's write-through stores) + relaxed RMW; wait spins with relaxed loads.
__device__ __forceinline__ void grid_barrier(int* __restrict__ gcnt,
                                             int* __restrict__ root,
                                             int barno, int g) {
  __syncthreads();
  if (threadIdx.x == 0) {
    asm volatile("s_waitcnt vmcnt(0)" ::: "memory");
    int t = __hip_atomic_fetch_add(&gcnt[g * 32], 1, __ATOMIC_RELAXED,
                                   __HIP_MEMORY_SCOPE_AGENT);
    if (t == barno * GRPSZ + (GRPSZ - 1)) {
      __hip_atomic_fetch_add(root, 1, __ATOMIC_RELAXED, __HIP_MEMORY_SCOPE_AGENT);
    }
    const int target = barno * NGRP + NGRP;
    while (__hip_atomic_load(root, __ATOMIC_RELAXED, __HIP_MEMORY_SCOPE_AGENT) < target) {
      __builtin_amdgcn_s_sleep(2);
    }
  }
  __syncthreads();
}

// One half-sweep for this block's 32 rows. S = A.B^T recomputed via split-bf16 MFMA.
// Opposite dual staged once into LDS via coherent loads; bf16 panels stay L2-hot
// (plain cached loads, never invalidated). Online LSE: one exp2 per element.
__device__ __forceinline__ void sweep_phase(
    const unsigned short* __restrict__ Ah, const unsigned short* __restrict__ Al,
    const unsigned short* __restrict__ Bh, const unsigned short* __restrict__ Bl,
    const float* __restrict__ sa, float* __restrict__ selfD,
    float* __restrict__ wself2, const float* __restrict__ woth2,
    float* __restrict__ slots, const bool isRow,
    const int b, const int i0, const int g, const float cst,
    float lm[32][4], float ls[32][4], float* __restrict__ wlds) {
  const int wq   = threadIdx.x >> 6;
  const int lane = threadIdx.x & 63;
  const int l15  = lane & 15, q = lane >> 4;

  // stage the opposite dual vector (coherent: written by other blocks/XCDs)
#pragma unroll
  for (int idx = 0; idx < NN / 256; idx++)
    wlds[idx * 256 + threadIdx.x] = coh_load(&woth2[b * NN + idx * 256 + threadIdx.x]);

  // fixed A fragments: rows i0+l15 (acc0) and i0+16+l15 (acc1), k-chunk q*8
  const size_t arow0 = ((size_t)(b * NN + i0 + l15)) * DIM + q * 8;
  const sh8 a0h = *(const sh8*)(Ah + arow0);
  const sh8 a0l = *(const sh8*)(Al + arow0);
  const sh8 a1h = *(const sh8*)(Ah + arow0 + 16 * DIM);
  const sh8 a1l = *(const sh8*)(Al + arow0 + 16 * DIM);

  float m2[8], ss[8];
#pragma unroll
  for (int r = 0; r < 8; r++) { m2[r] = -1e30f; ss[r] = 0.f; }

  __syncthreads();   // wlds ready

  const int jbase = wq * 512;
#pragma unroll 4
  for (int tj = 0; tj < 32; tj++) {
    const int j = jbase + tj * 16;
    const size_t brow = ((size_t)(b * NN + j + l15)) * DIM + q * 8;
    const sh8 bh = *(const sh8*)(Bh + brow);
    const sh8 bl = *(const sh8*)(Bl + brow);
    f32x4 acc0 = {0.f, 0.f, 0.f, 0.f};
    f32x4 acc1 = {0.f, 0.f, 0.f, 0.f};
    acc0 = __builtin_amdgcn_mfma_f32_16x16x32_bf16(a0h, bh, acc0, 0, 0, 0);
    acc1 = __builtin_amdgcn_mfma_f32_16x16x32_bf16(a1h, bh, acc1, 0, 0, 0);
    acc0 = __builtin_amdgcn_mfma_f32_16x16x32_bf16(a0h, bl, acc0, 0, 0, 0);
    acc1 = __builtin_amdgcn_mfma_f32_16x16x32_bf16(a1h, bl, acc1, 0, 0, 0);
    acc0 = __builtin_amdgcn_mfma_f32_16x16x32_bf16(a0l, bh, acc0, 0, 0, 0);
    acc1 = __builtin_amdgcn_mfma_f32_16x16x32_bf16(a1l, bh, acc1, 0, 0, 0);
    const float wj = wlds[j + l15];
#pragma unroll
    for (int r = 0; r < 8; r++) {
      const float S = (r < 4) ? acc0[r & 3] : acc1[r & 3];
      const float t = fmaf(S, C20L2E, wj);
      const float d = t - m2[r];
      const float e = ex2(-fabsf(d));           // single transcendental
      const bool up = d > 0.f;
      ss[r] = up ? fmaf(ss[r], e, 1.f) : (ss[r] + e);
      m2[r] = up ? t : m2[r];
    }
  }

  // reduce (m,s) across the 16 lanes that share a row
#pragma unroll
  for (int off = 1; off < 16; off <<= 1) {
#pragma unroll
    for (int r = 0; r < 8; r++) {
      const float mo = __shfl_xor(m2[r], off, 64);
      const float so = __shfl_xor(ss[r], off, 64);
      const float mn = fmaxf(m2[r], mo);
      ss[r] = ss[r] * ex2(m2[r] - mn) + so * ex2(mo - mn);
      m2[r] = mn;
    }
  }

  if (l15 == 0) {
#pragma unroll
    for (int r = 0; r < 4; r++) {
      lm[q * 4 + r][wq] = m2[r];          ls[q * 4 + r][wq] = ss[r];
      lm[16 + q * 4 + r][wq] = m2[4 + r]; ls[16 + q * 4 + r][wq] = ss[4 + r];
    }
  }
  __syncthreads();
  if (threadIdx.x < 32) {
    const int row = threadIdx.x;
    float m = lm[row][0], s = ls[row][0];
#pragma unroll
    for (int p = 1; p < 4; p++) {
      const float mo = lm[row][p], so = ls[row][p];
      const float mn = fmaxf(m, mo);
      s = s * ex2(m - mn) + so * ex2(mo - mn);
      m = mn;
    }
    const float lse = (m + lg2(s)) * LN2F;   // natural-log LSE
    const int gi = b * NN + i0 + row;
    const float sav = sa[gi];
    const float nu = cst + sav - EPSF * lse;
    const float old = coh_load(&selfD[gi]);   // own row, but keep one coherent path
    coh_store(&selfD[gi], nu);
    coh_store(&wself2[gi], (nu - sav) * C10L2E);
    if (isRow) {
      float du = fabsf(nu - old);
#pragma unroll
      for (int off = 1; off < 32; off <<= 1) du += __shfl_xor(du, off, 64);
      if (threadIdx.x == 0) atomicAdd(&slots[g * 32], du);  // device-scope
    }
  }
  __syncthreads();
}

// Persistent (plain-launch) kernel: whole Sinkhorn loop, one dispatch.
// 512 WGs x 256 thr; launch_bounds(256,4) -> VGPR<=128 -> capacity 4 WG/CU = 1024
// >= 512: all blocks resident with 2x slack -> software grid barrier is safe.
// Block mapping b = blk&7: round-robin XCD assignment pins each XCD to one batch
// -> per-XCD read-only footprint 512 KB, resident in its 4 MB L2 forever.
__global__ __launch_bounds__(256, 4) void solve_kernel(
    const unsigned short* __restrict__ xh, const unsigned short* __restrict__ xl,
    const unsigned short* __restrict__ yh, const unsigned short* __restrict__ yl,
    const float* __restrict__ sx, const float* __restrict__ sy,
    float* __restrict__ u, float* __restrict__ v,
    float* __restrict__ wu2, float* __restrict__ wv2,
    float* __restrict__ slots, int* __restrict__ gcnt,
    int* __restrict__ root, int* __restrict__ done,
    float emu, float enu) {
  __shared__ float lm[32][4];
  __shared__ float ls[32][4];
  __shared__ float wlds[NN];
  const int b  = blockIdx.x & 7;
  const int i0 = (blockIdx.x >> 3) * 32;
  const int g  = blockIdx.x & (NGRP - 1);
  int barno = 0;

  for (int it = 0; it < MAX_ITER; ++it) {
    // u-phase: rows of x vs all y, weights wv2 -> updates u, wu2, err slots
    sweep_phase(xh, xl, yh, yl, sx, u, wu2, wv2, slots, true, b, i0, g, emu,
                lm, ls, wlds);
    grid_barrier(gcnt, root, barno++, g);
    if (blockIdx.x == 0 && threadIdx.x == 0) {
      float e = 0.f;
      for (int s = 0; s < NSLOT; ++s) {
        e += coh_load(&slots[s * 32]);
        coh_store(&slots[s * 32], 0.f);
      }
      if (e * 0.125f < THRESHF)
        __hip_atomic_store(done, 1, __ATOMIC_RELAXED, __HIP_MEMORY_SCOPE_AGENT);
    }
    // v-phase: rows of y vs all x, weights (updated) wu2 -> updates v, wv2
    sweep_phase(yh, yl, xh, xl, sy, v, wv2, wu2, slots, false, b, i0, g, enu,
                lm, ls, wlds);
    grid_barrier(gcnt, root, barno++, g);
    if (__hip_atomic_load(done, __ATOMIC_RELAXED, __HIP_MEMORY_SCOPE_AGENT))
      break;   // converging iteration applied; remaining iterations frozen
  }
}

// C = sx_i + sy_j - 2S ; pi = exp2(wu2_i + wv2_j + 20log2e*S) ; cost[b] += pi*C
__global__ __launch_bounds__(256) void finalize_kernel(const unsigned short* __restrict__ xh,
                                                       const unsigned short* __restrict__ xl,
                                                       const unsigned short* __restrict__ yh,
                                                       const unsigned short* __restrict__ yl,
                                                       const float* __restrict__ sx,
                                                       const float* __restrict__ sy,
                                                       const float* __restrict__ wu2,
                                                       const float* __restrict__ wv2,
                                                       float* __restrict__ C,
                                                       float* __restrict__ pi,
                                                       float* __restrict__ cost) {
  const int b  = blockIdx.z;
  const int wv = threadIdx.x >> 6;
  const int lane = threadIdx.x & 63;
  const int l15 = lane & 15, q = lane >> 4;
  const int i0 = blockIdx.y * 128 + wv * 32;
  const int j0 = blockIdx.x * 256;

  const size_t arow0 = ((size_t)(b * NN + i0 + l15)) * DIM + q * 8;
  const sh8 a0h = *(const sh8*)(xh + arow0);
  const sh8 a0l = *(const sh8*)(xl + arow0);
  const sh8 a1h = *(const sh8*)(xh + arow0 + 16 * DIM);
  const sh8 a1l = *(const sh8*)(xl + arow0 + 16 * DIM);

  float sx0[8], wu0[8];
#pragma unroll
  for (int r = 0; r < 8; r++) {
    const int gi = b * NN + i0 + ((r < 4) ? (q * 4 + (r & 3)) : (16 + q * 4 + (r & 3)));
    sx0[r] = sx[gi];
    wu0[r] = wu2[gi];
  }

  float acc = 0.f;
#pragma unroll 2
  for (int tj = 0; tj < 16; tj++) {
    const int j = j0 + tj * 16;
    const size_t brow = ((size_t)(b * NN + j + l15)) * DIM + q * 8;
    const sh8 bh = *(const sh8*)(yh + brow);
    const sh8 bl = *(const sh8*)(yl + brow);
    f32x4 acc0 = {0.f, 0.f, 0.f, 0.f};
    f32x4 acc1 = {0.f, 0.f, 0.f, 0.f};
    acc0 = __builtin_amdgcn_mfma_f32_16x16x32_bf16(a0h, bh, acc0, 0, 0, 0);
    acc1 = __builtin_amdgcn_mfma_f32_16x16x32_bf16(a1h, bh, acc1, 0, 0, 0);
    acc0 = __builtin_amdgcn_mfma_f32_16x16x32_bf16(a0h, bl, acc0, 0, 0, 0);
    acc1 = __builtin_amdgcn_mfma_f32_16x16x32_bf16(a1h, bl, acc1, 0, 0, 0);
    acc0 = __builtin_amdgcn_mfma_f32_16x16x32_bf16(a0l, bh, acc0, 0, 0, 0);
    acc1 = __builtin_amdgcn_mfma_f32_16x16x32_bf16(a1l, bh, acc1, 0, 0, 0);
    const int gj = b * NN + j + l15;
    const float syj = sy[gj];
    const float wvj = wv2[gj];
#pragma unroll
    for (int r = 0; r < 8; r++) {
      const float S = (r < 4) ? acc0[r & 3] : acc1[r & 3];
      const int irow = i0 + ((r < 4) ? (q * 4 + (r & 3)) : (16 + q * 4 + (r & 3)));
      const float Cv = fmaf(-2.f, S, sx0[r] + syj);
      const float p  = ex2(fmaf(S, C20L2E, wu0[r] + wvj));
      const size_t addr = ((size_t)(b * NN + irow)) * NN + j + l15;
      C[addr]  = Cv;
      pi[addr] = p;
      acc = fmaf(p, Cv, acc);
    }
  }
#pragma unroll
  for (int off = 1; off < 64; off <<= 1) acc += __shfl_xor(acc, off, 64);
  __shared__ float red[4];
  if (lane == 0) red[wv] = acc;
  __syncthreads();
  if (threadIdx.x == 0) atomicAdd(&cost[b], red[0] + red[1] + red[2] + red[3]);
}

extern "C" void kernel_launch(void* const* d_in, const int* in_sizes, int n_in,
                              void* d_out, int out_size, void* d_ws, size_t ws_size,
                              hipStream_t stream) {
  const float* x = (const float*)d_in[0];
  const float* y = (const float*)d_in[1];
  float* out  = (float*)d_out;
  float* cost = out;                              // [8]
  float* pi   = out + 8;                          // [8,2048,2048]
  float* C    = out + 8 + (size_t)BB * NN * NN;   // [8,2048,2048]

  float* ws = (float*)d_ws;
  const int BN = BB * NN;                         // 16384
  float* u   = ws;               // [16384]
  float* v   = ws + BN;
  float* wu2 = ws + 2 * BN;
  float* wv2 = ws + 3 * BN;
  float* sx  = ws + 4 * BN;
  float* sy  = ws + 5 * BN;
  float* slots = ws + 6 * BN;                     // 16 slots, stride 32 floats
  int*   gcnt  = (int*)(ws + 6 * BN + 512);       // 16 counters, stride 32 ints
  int*   root  = gcnt + 512;
  int*   done  = gcnt + 513;
  unsigned short* xh = (unsigned short*)(ws + 6 * BN + 512 + 576);
  const size_t NE = (size_t)BB * NN * DIM;        // 524288
  unsigned short* xl = xh + NE;
  unsigned short* yh = xh + 2 * NE;
  unsigned short* yl = xh + 3 * NE;

  // zero u,v,slots,barrier counters,done (prep rewrites wu2/wv2/sx/sy)
  hipMemsetAsync(d_ws, 0, (size_t)(6 * BN + 512 + 576) * sizeof(float), stream);
  hipMemsetAsync(d_out, 0, 8 * sizeof(float), stream);

  prep_kernel<<<2048, 256, 0, stream>>>(x, xh, xl, sx, wu2);
  prep_kernel<<<2048, 256, 0, stream>>>(y, yh, yl, sy, wv2);

  const float emu = (float)(0.1 * log(1.0 / 2048.0 + 1e-8));
  const float enu = emu;

  solve_kernel<<<512, 256, 0, stream>>>(xh, xl, yh, yl, sx, sy, u, v, wu2, wv2,
                                        slots, gcnt, root, done, emu, enu);

  finalize_kernel<<<dim3(8, 16, BB), 256, 0, stream>>>(xh, xl, yh, yl, sx, sy,
                                                       wu2, wv2, C, pi, cost);
}